// Round 11
// baseline (299.543 us; speedup 1.0000x reference)
//
#include <hip/hip_runtime.h>
#include <hip/hip_bf16.h>

// GAT 2-layer inference, round 11:
//  - NEW: gemm2 fused into g1 -> g1f_kernel (782 blocks x 1024 thr, 16 waves):
//    phase A wave-per-dst gather (same shape as the measured-72.7us g1, 1.5x wave
//    oversubscription) writing relu(agg+b1) bf16 straight into the LDS x2 tile;
//    phase B 16 waves x one 16x16 MFMA tile = full 128x32 gemm2; phase C h2 +
//    attention dots. Deletes gemm2 launch + the whole agg1 HBM round trip (51 MB).
//  - KEEP: fused1 (gemm1 MFMA + binA overlapped), binB, g2, bf16 h1/h2.
// N=100000, E=1600000 (+N self loops), IN_C=128, L1: 4 heads x 32, L2: 1 head x 32.
// Softmax as fused weighted mean, no max-subtraction (validated rounds 1-10).
// g1 gather sits at the ~3.9 TB/s past-L2 random-gather plateau (240 MB fetch);
// rounds 6/7/10 proved ILP/VALU restructuring neutral there.

#define NSLOPE 0.2f
#define GSTRIDE 136    // bf16 LDS row stride for MFMA tiles (68 words == 4 mod 32)
#define NB_MAX 400     // bins = ceil(N/256) = 391 for N=100k
#define CHUNK 4096     // edges per block in binA role (16 per thread)
#define CAP 5632       // per-bin capacity (mean 4352, sigma 66 -> ~19 sigma margin)

typedef __attribute__((ext_vector_type(8))) short short8;
typedef __attribute__((ext_vector_type(4))) float floatx4;

__device__ __forceinline__ float leaky(float v) { return v > 0.f ? v : NSLOPE * v; }

__device__ __forceinline__ unsigned short f2bf(float f) {
  __hip_bfloat16 b = __float2bfloat16(f);
  return *reinterpret_cast<unsigned short*>(&b);
}
__device__ __forceinline__ float bf2f(unsigned int u) {  // low 16 bits hold bf16
  return __uint_as_float(u << 16);
}
__device__ __forceinline__ unsigned int pack2(float a, float b) {
  return (unsigned int)f2bf(a) | ((unsigned int)f2bf(b) << 16);
}

// ---------------- fused1: gemm1 (blocks < g1blocks) + binA (rest) ----------------
__global__ __launch_bounds__(256, 2) void fused1_kernel(
    const float* __restrict__ x, const float* __restrict__ W,
    const float* __restrict__ atts, const float* __restrict__ attd,
    unsigned short* __restrict__ h, float* __restrict__ asrc, float* __restrict__ adst,
    int n, int g1blocks,
    const int* __restrict__ ei, int* __restrict__ bincur,
    unsigned int* __restrict__ staging, int E, int ET, int nb) {
  __shared__ __align__(16) unsigned char smem[70656];
  const int tid = threadIdx.x;

  if (blockIdx.x < g1blocks) {
    // ---------- gemm1 role: h1 = bf16(x @ W1), asrc1/adst1 dots ----------
    unsigned short* xs = (unsigned short*)smem;            // 128*GSTRIDE shorts
    unsigned short* wt = (unsigned short*)(smem + 34816);  // 128*GSTRIDE shorts
    float* att_s = (float*)(smem + 69632);                 // 128 f
    float* att_d = (float*)(smem + 70144);                 // 128 f
    const int row0 = blockIdx.x * 128;

    if (tid < 128) { att_s[tid] = atts[tid]; att_d[tid] = attd[tid]; }

    const float4* w4 = (const float4*)W;
#pragma unroll
    for (int i = 0; i < 16; i++) {
      int idx = tid + i * 256;         // 4096 float4s
      int k = idx >> 5, n0 = (idx & 31) * 4;
      float4 v = w4[idx];
      float vv[4] = {v.x, v.y, v.z, v.w};
#pragma unroll
      for (int jj = 0; jj < 4; jj++) {
        int j = (jj + tid) & 3;
        wt[(n0 + j) * GSTRIDE + k] = f2bf(vv[j]);
      }
    }

    const float4* x4 = (const float4*)x;
#pragma unroll
    for (int i = 0; i < 16; i++) {
      int idx = tid + i * 256;
      int r = idx >> 5, c4 = idx & 31;
      float4 v = make_float4(0.f, 0.f, 0.f, 0.f);
      if (row0 + r < n) v = x4[(size_t)(row0 + r) * 32 + c4];
      unsigned int* p = (unsigned int*)&xs[r * GSTRIDE + c4 * 4];
      p[0] = pack2(v.x, v.y);
      p[1] = pack2(v.z, v.w);
    }
    __syncthreads();

    const int l = tid & 63;
    const int w = tid >> 6;
    const int mrow = l & 15;
    const int q = l >> 4;
    floatx4 acc[2][8];
#pragma unroll
    for (int mt = 0; mt < 2; mt++)
#pragma unroll
      for (int nt = 0; nt < 8; nt++) acc[mt][nt] = (floatx4){0.f, 0.f, 0.f, 0.f};

#pragma unroll
    for (int ks = 0; ks < 4; ks++) {
      const int k0 = ks * 32 + q * 8;
      short8 a0 = *(const short8*)&xs[(w * 32 + mrow) * GSTRIDE + k0];
      short8 a1 = *(const short8*)&xs[(w * 32 + 16 + mrow) * GSTRIDE + k0];
#pragma unroll
      for (int nt = 0; nt < 8; nt++) {
        short8 b = *(const short8*)&wt[(nt * 16 + mrow) * GSTRIDE + k0];
        acc[0][nt] = __builtin_amdgcn_mfma_f32_16x16x32_bf16(a0, b, acc[0][nt], 0, 0, 0);
        acc[1][nt] = __builtin_amdgcn_mfma_f32_16x16x32_bf16(a1, b, acc[1][nt], 0, 0, 0);
      }
    }
    __syncthreads();

#pragma unroll
    for (int mt = 0; mt < 2; mt++)
#pragma unroll
      for (int nt = 0; nt < 8; nt++)
#pragma unroll
        for (int i = 0; i < 4; i++) {
          int r = w * 32 + mt * 16 + q * 4 + i;
          xs[r * GSTRIDE + nt * 16 + mrow] = f2bf(acc[mt][nt][i]);
        }
    __syncthreads();

#pragma unroll
    for (int i = 0; i < 8; i++) {
      int idx = tid + i * 256;        // 2048
      int r = idx >> 4, c8 = (idx & 15) * 8;
      if (row0 + r < n) {
        unsigned int* p = (unsigned int*)&xs[r * GSTRIDE + c8];
        uint4 v = make_uint4(p[0], p[1], p[2], p[3]);
        *(uint4*)(h + (size_t)(row0 + r) * 128 + c8) = v;
      }
    }

#pragma unroll
    for (int rr = 0; rr < 2; rr++) {
      int row = (tid >> 2) + rr * 64;
      int head = tid & 3;
      float ss = 0.f, sd = 0.f;
#pragma unroll
      for (int c = 0; c < 32; c++) {
        int cr = (c + tid) & 31;
        float hv = bf2f(xs[row * GSTRIDE + head * 32 + cr]);
        ss += hv * att_s[head * 32 + cr];
        sd += hv * att_d[head * 32 + cr];
      }
      if (row0 + row < n) {
        asrc[(size_t)(row0 + row) * 4 + head] = ss;
        adst[(size_t)(row0 + row) * 4 + head] = sd;
      }
    }
  } else {
    // ---------- binA role: scatter packed (src, dst&255) into fixed-stride bins ----------
    int* hist  = (int*)smem;           // NB_MAX
    int* run   = (int*)(smem + 1600);  // NB_MAX
    int* rbase = (int*)(smem + 3200);  // NB_MAX
    const int base = (blockIdx.x - g1blocks) * CHUNK;
    for (int i = tid; i < nb; i += 256) { hist[i] = 0; run[i] = 0; }
    __syncthreads();
    int se[16], de[16];
#pragma unroll
    for (int j = 0; j < 16; j++) {
      int idx = base + j * 256 + tid;
      if (idx < ET) {
        if (idx < E) { se[j] = ei[idx]; de[j] = ei[E + idx]; }
        else         { se[j] = de[j] = idx - E; }
        atomicAdd(&hist[de[j] >> 8], 1);
      } else de[j] = -1;
    }
    __syncthreads();
    for (int i = tid; i < nb; i += 256)
      rbase[i] = hist[i] ? (i * CAP + atomicAdd(&bincur[i], hist[i])) : 0;
    __syncthreads();
#pragma unroll
    for (int j = 0; j < 16; j++) {
      if (de[j] >= 0) {
        int b = de[j] >> 8;
        int ofs = atomicAdd(&run[b], 1);
        staging[(size_t)rbase[b] + ofs] =
            (unsigned)se[j] | ((unsigned)(de[j] & 255) << 17);
      }
    }
  }
}

// ---------------- binB: per bin -> rowbeg/rowend + bucket placement (fixed-stride space) ----------------
__global__ __launch_bounds__(256) void binB_kernel(const unsigned int* __restrict__ staging,
                                                   const int* __restrict__ bincur,
                                                   int* __restrict__ rowbeg,
                                                   int* __restrict__ rowend,
                                                   int* __restrict__ bucket, int n) {
  __shared__ int cnt[256];
  __shared__ int cur[256];
  const int b = blockIdx.x;
  const int t = threadIdx.x;
  const int d0 = b << 8;
  const int nd = min(256, n - d0);
  const int base = b * CAP;
  const int rcnt = bincur[b];
  cnt[t] = 0;
  __syncthreads();
  for (int j = t; j < rcnt; j += 256) {
    unsigned int r = staging[(size_t)base + j];
    atomicAdd(&cnt[r >> 17], 1);
  }
  __syncthreads();
  int v = cnt[t];
  cur[t] = v;
  __syncthreads();
  for (int off = 1; off < 256; off <<= 1) {
    int add = (t >= off) ? cur[t - off] : 0;
    __syncthreads();
    cur[t] += add;
    __syncthreads();
  }
  int start = base + cur[t] - v;  // exclusive prefix within bin
  if (t < nd) { rowbeg[d0 + t] = start; rowend[d0 + t] = start + v; }
  __syncthreads();
  cur[t] = start;
  __syncthreads();
  for (int j = t; j < rcnt; j += 256) {
    unsigned int r = staging[(size_t)base + j];
    int pos = atomicAdd(&cur[r >> 17], 1);
    bucket[pos] = (int)(r & 0x1FFFFu);
  }
}

// ---------------- g1f: gather layer1 (wave per dst) + fused gemm2 + a2 dots ----------------
// 1024 thr / 16 waves per block; block owns 128 dsts.
// Phase A: wave wv gathers dsts wv, wv+16, ... (8 per wave); 8-edge groups of 8 lanes;
//          writes relu(num/den + b1) bf16 into LDS x2 tile.
// Phase B: wave wv computes 16x16 output tile (mt=wv>>1, nt=wv&1) via 4 MFMAs.
// Phase C: coalesced h2 write + attention dots for layer 2.
__global__ __launch_bounds__(1024, 8) void g1f_kernel(
    const int* __restrict__ rowbeg, const int* __restrict__ rowend,
    const int* __restrict__ bucket,
    const float* __restrict__ asrc, const float* __restrict__ adst,
    const unsigned int* __restrict__ h,   // h1 bf16x2, row stride 64
    const float* __restrict__ b1,
    const float* __restrict__ W2,         // 128x32 fp32
    const float* __restrict__ atts2, const float* __restrict__ attd2,
    unsigned short* __restrict__ h2,      // out bf16
    float* __restrict__ asrc2, float* __restrict__ adst2, int n) {
  __shared__ __align__(16) unsigned short xs[128 * GSTRIDE];  // x2 tile bf16 (34.8 KB)
  __shared__ __align__(16) unsigned short wt[32 * GSTRIDE];   // W2^T bf16 (8.7 KB)
  __shared__ __align__(16) unsigned short hs[128 * 36];       // h2 tile bf16 (9.2 KB)
  __shared__ float b1s[128];
  __shared__ float att_s[32], att_d[32];
  const int tid = threadIdx.x;
  const int row0 = blockIdx.x * 128;

  // stage W2^T (1024 float4s, one per thread) + b1 + att vectors
  {
    int k = tid >> 3, n0 = (tid & 7) * 4;
    float4 v = ((const float4*)W2)[tid];
    float vv[4] = {v.x, v.y, v.z, v.w};
#pragma unroll
    for (int jj = 0; jj < 4; jj++) {
      int j = (jj + tid) & 3;
      wt[(n0 + j) * GSTRIDE + k] = f2bf(vv[j]);
    }
  }
  if (tid < 128) b1s[tid] = b1[tid];
  else if (tid < 160) att_s[tid - 128] = atts2[tid - 128];
  else if (tid < 192) att_d[tid - 160] = attd2[tid - 160];
  __syncthreads();

  // ---- Phase A: gather ----
  const int wv = tid >> 6;
  const int lane = tid & 63;
  const int g = lane >> 3;
  const int l8 = lane & 7;
  const int head = l8 >> 1;
  for (int dd = wv; dd < 128; dd += 16) {
    const int d = row0 + dd;
    if (d < n) {
      const float ad = adst[(size_t)d * 4 + head];
      const int beg = rowbeg[d], end = rowend[d];
      float num[16];
#pragma unroll
      for (int j = 0; j < 16; j++) num[j] = 0.f;
      float den = 0.f;

      int i = beg + g;
      if (i < end) {
        int s = bucket[i];
        for (;;) {
          float a = asrc[(size_t)s * 4 + head];
          const uint4* hp = (const uint4*)(h + (size_t)s * 64 + l8 * 8);
          uint4 h0 = hp[0];
          uint4 h1v = hp[1];
          int i2 = i + 8;
          int s2 = (i2 < end) ? bucket[i2] : 0;
          float w = __expf(leaky(a + ad));
          den += w;
          num[0]  += w * bf2f(h0.x & 0xffffu);  num[1]  += w * bf2f(h0.x >> 16);
          num[2]  += w * bf2f(h0.y & 0xffffu);  num[3]  += w * bf2f(h0.y >> 16);
          num[4]  += w * bf2f(h0.z & 0xffffu);  num[5]  += w * bf2f(h0.z >> 16);
          num[6]  += w * bf2f(h0.w & 0xffffu);  num[7]  += w * bf2f(h0.w >> 16);
          num[8]  += w * bf2f(h1v.x & 0xffffu); num[9]  += w * bf2f(h1v.x >> 16);
          num[10] += w * bf2f(h1v.y & 0xffffu); num[11] += w * bf2f(h1v.y >> 16);
          num[12] += w * bf2f(h1v.z & 0xffffu); num[13] += w * bf2f(h1v.z >> 16);
          num[14] += w * bf2f(h1v.w & 0xffffu); num[15] += w * bf2f(h1v.w >> 16);
          if (i2 >= end) break;
          i = i2; s = s2;
        }
      }
#pragma unroll
      for (int j = 0; j < 16; j++) {
        num[j] += __shfl_xor(num[j], 8, 64);
        num[j] += __shfl_xor(num[j], 16, 64);
        num[j] += __shfl_xor(num[j], 32, 64);
      }
      den += __shfl_xor(den, 8, 64);
      den += __shfl_xor(den, 16, 64);
      den += __shfl_xor(den, 32, 64);
      if (g == 0) {
        float inv = 1.f / (den + 1e-16f);
        unsigned int* p = (unsigned int*)&xs[dd * GSTRIDE + l8 * 16];
#pragma unroll
        for (int j = 0; j < 8; j++) {
          float lo = fmaxf(num[j * 2] * inv + b1s[l8 * 16 + j * 2], 0.f);
          float hi = fmaxf(num[j * 2 + 1] * inv + b1s[l8 * 16 + j * 2 + 1], 0.f);
          p[j] = pack2(lo, hi);
        }
      }
    }
    // rows >= n left as garbage: MFMA rows are independent, outputs guarded.
  }
  __syncthreads();

  // ---- Phase B: gemm2 MFMA. wave wv -> 16x16 tile (mt = wv>>1, nt = wv&1) ----
  {
    const int mrow = lane & 15;
    const int q = lane >> 4;
    const int mt = wv >> 1;
    const int nt = wv & 1;
    floatx4 acc = (floatx4){0.f, 0.f, 0.f, 0.f};
#pragma unroll
    for (int ks = 0; ks < 4; ks++) {
      const int k0 = ks * 32 + q * 8;
      short8 a = *(const short8*)&xs[(mt * 16 + mrow) * GSTRIDE + k0];
      short8 b = *(const short8*)&wt[(nt * 16 + mrow) * GSTRIDE + k0];
      acc = __builtin_amdgcn_mfma_f32_16x16x32_bf16(a, b, acc, 0, 0, 0);
    }
#pragma unroll
    for (int i = 0; i < 4; i++)
      hs[(mt * 16 + q * 4 + i) * 36 + nt * 16 + mrow] = f2bf(acc[i]);
  }
  __syncthreads();

  // ---- Phase C: h2 write (128 rows x 8 uint2; one per thread) + a2 dots ----
  {
    int r = tid >> 3, c4 = (tid & 7) * 4;
    if (row0 + r < n) {
      unsigned int* p = (unsigned int*)&hs[r * 36 + c4];
      *(uint2*)(h2 + (size_t)(row0 + r) * 32 + c4) = make_uint2(p[0], p[1]);
    }
  }
  if (tid < 128 && row0 + tid < n) {
    float ss = 0.f, sd = 0.f;
#pragma unroll
    for (int c = 0; c < 32; c++) {
      int cr = (c + tid) & 31;
      float hv = bf2f(hs[tid * 36 + cr]);
      ss += hv * att_s[cr];
      sd += hv * att_d[cr];
    }
    asrc2[row0 + tid] = ss;
    adst2[row0 + tid] = sd;
  }
}

// ---------------- g2: wave per dst, 8 edges/iter (8-lane groups) ----------------
__global__ __launch_bounds__(256) void g2_kernel(const int* __restrict__ rowbeg,
                                                 const int* __restrict__ rowend,
                                                 const int* __restrict__ bucket,
                                                 const float* __restrict__ asrc,
                                                 const float* __restrict__ adst,
                                                 const unsigned int* __restrict__ h2,  // bf16x2, row stride 16
                                                 const float* __restrict__ b2,
                                                 float* __restrict__ out, int n) {
  const int lane = threadIdx.x & 63;
  const int g = lane >> 3;
  const int l8 = lane & 7;
  const int d = blockIdx.x * 4 + (threadIdx.x >> 6);
  if (d >= n) return;
  const float ad = adst[d];
  const int beg = rowbeg[d], end = rowend[d];
  float num[4];
#pragma unroll
  for (int j = 0; j < 4; j++) num[j] = 0.f;
  float den = 0.f;

  int i = beg + g;
  if (i < end) {
    int s = bucket[i];
    for (;;) {
      float a = asrc[s];
      uint2 hv = *(const uint2*)(h2 + (size_t)s * 16 + l8 * 2);
      int i2 = i + 8;
      int s2 = (i2 < end) ? bucket[i2] : 0;
      float w = __expf(leaky(a + ad));
      den += w;
      num[0] += w * bf2f(hv.x & 0xffffu); num[1] += w * bf2f(hv.x >> 16);
      num[2] += w * bf2f(hv.y & 0xffffu); num[3] += w * bf2f(hv.y >> 16);
      if (i2 >= end) break;
      i = i2; s = s2;
    }
  }
#pragma unroll
  for (int j = 0; j < 4; j++) {
    num[j] += __shfl_xor(num[j], 8, 64);
    num[j] += __shfl_xor(num[j], 16, 64);
    num[j] += __shfl_xor(num[j], 32, 64);
  }
  den += __shfl_xor(den, 8, 64);
  den += __shfl_xor(den, 16, 64);
  den += __shfl_xor(den, 32, 64);
  if (g == 0) {
    float inv = 1.f / (den + 1e-16f);
    float4 bb = ((const float4*)b2)[l8];  // b2: 32 floats = 8 float4; l8 in [0,8)
    *(float4*)(out + (size_t)d * 32 + l8 * 4) =
        make_float4(num[0] * inv + bb.x, num[1] * inv + bb.y,
                    num[2] * inv + bb.z, num[3] * inv + bb.w);
  }
}

extern "C" void kernel_launch(void* const* d_in, const int* in_sizes, int n_in,
                              void* d_out, int out_size, void* d_ws, size_t ws_size,
                              hipStream_t stream) {
  const float* x = (const float*)d_in[0];
  const int* ei = (const int*)d_in[1];
  const float* W1 = (const float*)d_in[2];
  const float* atts1 = (const float*)d_in[3];
  const float* attd1 = (const float*)d_in[4];
  const float* b1 = (const float*)d_in[5];
  const float* W2 = (const float*)d_in[6];
  const float* atts2 = (const float*)d_in[7];
  const float* attd2 = (const float*)d_in[8];
  const float* b2 = (const float*)d_in[9];
  float* out = (float*)d_out;

  const int N = in_sizes[0] / 128;
  const int E = in_sizes[1] / 2;
  const int ET = E + N;
  const int NB = (N + 255) >> 8;            // 391 bins (256 dsts each)
  const int NCH = (ET + CHUNK - 1) / CHUNK; // 416 binA-role blocks
  const int G1B = (N + 127) / 128;          // 782 gemm1-role blocks

  // workspace (~73 MB):
  float* wsf = (float*)d_ws;
  float* asrc1 = wsf;                                   // 4N f
  float* adst1 = asrc1 + (size_t)N * 4;                 // 4N f
  float* asrc2 = adst1 + (size_t)N * 4;                 // N f
  float* adst2 = asrc2 + (size_t)N;                     // N f
  unsigned short* h1 = (unsigned short*)(adst2 + (size_t)N);  // 128N bf16
  unsigned short* h2 = h1 + (size_t)N * 128;            // 32N bf16
  int* rowbeg = (int*)(h2 + (size_t)N * 32);            // N
  int* rowend = rowbeg + N;                             // N
  int* bucket = rowend + N;                             // NB*CAP (fixed-stride space)
  unsigned int* staging = (unsigned int*)(bucket + (size_t)NB * CAP);  // NB*CAP
  int* bincur = (int*)(staging + (size_t)NB * CAP);     // NB

  hipMemsetAsync(bincur, 0, NB * sizeof(int), stream);
  fused1_kernel<<<G1B + NCH, 256, 0, stream>>>(x, W1, atts1, attd1, h1, asrc1, adst1,
                                               N, G1B, ei, bincur, staging, E, ET, NB);
  binB_kernel<<<NB, 256, 0, stream>>>(staging, bincur, rowbeg, rowend, bucket, N);
  g1f_kernel<<<G1B, 1024, 0, stream>>>(rowbeg, rowend, bucket, asrc1, adst1,
                                       (const unsigned int*)h1, b1, W2, atts2, attd2,
                                       h2, asrc2, adst2, N);
  g2_kernel<<<(N + 3) / 4, 256, 0, stream>>>(rowbeg, rowend, bucket, asrc2, adst2,
                                             (const unsigned int*)h2, b2, out, N);
}

// Round 12
// 285.315 us; speedup vs baseline: 1.0499x; 1.0499x over previous
//
#include <hip/hip_runtime.h>
#include <hip/hip_bf16.h>

// GAT 2-layer inference, round 12 (= round 10 structure + binB-1024 + relu/bias fused into g1):
//  - REVERTED round 11's g1f fat-block fusion: 782x1024 blocks ran in 2 scheduling rounds
//    (2nd half-empty) + 16-wave barrier imbalance -> gather throughput 3.74->2.35 TB/s.
//    Gathers must stay in many small independent blocks (also proven by round 9).
//  - binB now 1024 thr/block: 256-thr version filled only 19% of the machine.
//  - g1 epilogue writes x2 = relu(agg+b1) bf16 directly; gemm2 staging is a pure copy.
//  - KEEP: fused1 (gemm1 MFMA + binA overlapped), bf16 h1/h2/x2, MFMA gemm2, g2.
// N=100000, E=1600000 (+N self loops), IN_C=128, L1: 4 heads x 32, L2: 1 head x 32.
// Softmax as fused weighted mean, no max-subtraction (validated rounds 1-11).
// g1 sits at the ~3.9 TB/s past-L2 random-gather plateau (240 MB fetch); rounds 6/7/10/11
// proved ILP/VALU/fat-block restructuring neutral-or-worse there. fp8 h1 ruled out by
// error budget (est. absmax ~0.02 > 0.0184 threshold).

#define NSLOPE 0.2f
#define GSTRIDE 136    // bf16 LDS row stride for MFMA tiles (68 words == 4 mod 32)
#define NB_MAX 400     // bins = ceil(N/256) = 391 for N=100k
#define CHUNK 4096     // edges per block in binA role (16 per thread)
#define CAP 5632       // per-bin capacity (mean 4352, sigma 66 -> ~19 sigma margin)

typedef __attribute__((ext_vector_type(8))) short short8;
typedef __attribute__((ext_vector_type(4))) float floatx4;

__device__ __forceinline__ float leaky(float v) { return v > 0.f ? v : NSLOPE * v; }

__device__ __forceinline__ unsigned short f2bf(float f) {
  __hip_bfloat16 b = __float2bfloat16(f);
  return *reinterpret_cast<unsigned short*>(&b);
}
__device__ __forceinline__ float bf2f(unsigned int u) {  // low 16 bits hold bf16
  return __uint_as_float(u << 16);
}
__device__ __forceinline__ unsigned int pack2(float a, float b) {
  return (unsigned int)f2bf(a) | ((unsigned int)f2bf(b) << 16);
}

// ---------------- fused1: gemm1 (blocks < g1blocks) + binA (rest) ----------------
__global__ __launch_bounds__(256, 2) void fused1_kernel(
    const float* __restrict__ x, const float* __restrict__ W,
    const float* __restrict__ atts, const float* __restrict__ attd,
    unsigned short* __restrict__ h, float* __restrict__ asrc, float* __restrict__ adst,
    int n, int g1blocks,
    const int* __restrict__ ei, int* __restrict__ bincur,
    unsigned int* __restrict__ staging, int E, int ET, int nb) {
  __shared__ __align__(16) unsigned char smem[70656];
  const int tid = threadIdx.x;

  if (blockIdx.x < g1blocks) {
    // ---------- gemm1 role: h1 = bf16(x @ W1), asrc1/adst1 dots ----------
    unsigned short* xs = (unsigned short*)smem;            // 128*GSTRIDE shorts
    unsigned short* wt = (unsigned short*)(smem + 34816);  // 128*GSTRIDE shorts
    float* att_s = (float*)(smem + 69632);                 // 128 f
    float* att_d = (float*)(smem + 70144);                 // 128 f
    const int row0 = blockIdx.x * 128;

    if (tid < 128) { att_s[tid] = atts[tid]; att_d[tid] = attd[tid]; }

    const float4* w4 = (const float4*)W;
#pragma unroll
    for (int i = 0; i < 16; i++) {
      int idx = tid + i * 256;         // 4096 float4s
      int k = idx >> 5, n0 = (idx & 31) * 4;
      float4 v = w4[idx];
      float vv[4] = {v.x, v.y, v.z, v.w};
#pragma unroll
      for (int jj = 0; jj < 4; jj++) {
        int j = (jj + tid) & 3;
        wt[(n0 + j) * GSTRIDE + k] = f2bf(vv[j]);
      }
    }

    const float4* x4 = (const float4*)x;
#pragma unroll
    for (int i = 0; i < 16; i++) {
      int idx = tid + i * 256;
      int r = idx >> 5, c4 = idx & 31;
      float4 v = make_float4(0.f, 0.f, 0.f, 0.f);
      if (row0 + r < n) v = x4[(size_t)(row0 + r) * 32 + c4];
      unsigned int* p = (unsigned int*)&xs[r * GSTRIDE + c4 * 4];
      p[0] = pack2(v.x, v.y);
      p[1] = pack2(v.z, v.w);
    }
    __syncthreads();

    const int l = tid & 63;
    const int w = tid >> 6;
    const int mrow = l & 15;
    const int q = l >> 4;
    floatx4 acc[2][8];
#pragma unroll
    for (int mt = 0; mt < 2; mt++)
#pragma unroll
      for (int nt = 0; nt < 8; nt++) acc[mt][nt] = (floatx4){0.f, 0.f, 0.f, 0.f};

#pragma unroll
    for (int ks = 0; ks < 4; ks++) {
      const int k0 = ks * 32 + q * 8;
      short8 a0 = *(const short8*)&xs[(w * 32 + mrow) * GSTRIDE + k0];
      short8 a1 = *(const short8*)&xs[(w * 32 + 16 + mrow) * GSTRIDE + k0];
#pragma unroll
      for (int nt = 0; nt < 8; nt++) {
        short8 b = *(const short8*)&wt[(nt * 16 + mrow) * GSTRIDE + k0];
        acc[0][nt] = __builtin_amdgcn_mfma_f32_16x16x32_bf16(a0, b, acc[0][nt], 0, 0, 0);
        acc[1][nt] = __builtin_amdgcn_mfma_f32_16x16x32_bf16(a1, b, acc[1][nt], 0, 0, 0);
      }
    }
    __syncthreads();

#pragma unroll
    for (int mt = 0; mt < 2; mt++)
#pragma unroll
      for (int nt = 0; nt < 8; nt++)
#pragma unroll
        for (int i = 0; i < 4; i++) {
          int r = w * 32 + mt * 16 + q * 4 + i;
          xs[r * GSTRIDE + nt * 16 + mrow] = f2bf(acc[mt][nt][i]);
        }
    __syncthreads();

#pragma unroll
    for (int i = 0; i < 8; i++) {
      int idx = tid + i * 256;        // 2048
      int r = idx >> 4, c8 = (idx & 15) * 8;
      if (row0 + r < n) {
        unsigned int* p = (unsigned int*)&xs[r * GSTRIDE + c8];
        uint4 v = make_uint4(p[0], p[1], p[2], p[3]);
        *(uint4*)(h + (size_t)(row0 + r) * 128 + c8) = v;
      }
    }

#pragma unroll
    for (int rr = 0; rr < 2; rr++) {
      int row = (tid >> 2) + rr * 64;
      int head = tid & 3;
      float ss = 0.f, sd = 0.f;
#pragma unroll
      for (int c = 0; c < 32; c++) {
        int cr = (c + tid) & 31;
        float hv = bf2f(xs[row * GSTRIDE + head * 32 + cr]);
        ss += hv * att_s[head * 32 + cr];
        sd += hv * att_d[head * 32 + cr];
      }
      if (row0 + row < n) {
        asrc[(size_t)(row0 + row) * 4 + head] = ss;
        adst[(size_t)(row0 + row) * 4 + head] = sd;
      }
    }
  } else {
    // ---------- binA role: scatter packed (src, dst&255) into fixed-stride bins ----------
    int* hist  = (int*)smem;           // NB_MAX
    int* run   = (int*)(smem + 1600);  // NB_MAX
    int* rbase = (int*)(smem + 3200);  // NB_MAX
    const int base = (blockIdx.x - g1blocks) * CHUNK;
    for (int i = tid; i < nb; i += 256) { hist[i] = 0; run[i] = 0; }
    __syncthreads();
    int se[16], de[16];
#pragma unroll
    for (int j = 0; j < 16; j++) {
      int idx = base + j * 256 + tid;
      if (idx < ET) {
        if (idx < E) { se[j] = ei[idx]; de[j] = ei[E + idx]; }
        else         { se[j] = de[j] = idx - E; }
        atomicAdd(&hist[de[j] >> 8], 1);
      } else de[j] = -1;
    }
    __syncthreads();
    for (int i = tid; i < nb; i += 256)
      rbase[i] = hist[i] ? (i * CAP + atomicAdd(&bincur[i], hist[i])) : 0;
    __syncthreads();
#pragma unroll
    for (int j = 0; j < 16; j++) {
      if (de[j] >= 0) {
        int b = de[j] >> 8;
        int ofs = atomicAdd(&run[b], 1);
        staging[(size_t)rbase[b] + ofs] =
            (unsigned)se[j] | ((unsigned)(de[j] & 255) << 17);
      }
    }
  }
}

// ---------------- binB (1024 thr): per bin -> rowbeg/rowend + bucket placement ----------------
__global__ __launch_bounds__(1024) void binB_kernel(const unsigned int* __restrict__ staging,
                                                    const int* __restrict__ bincur,
                                                    int* __restrict__ rowbeg,
                                                    int* __restrict__ rowend,
                                                    int* __restrict__ bucket, int n) {
  __shared__ int cnt[256];
  __shared__ int cur[256];
  const int b = blockIdx.x;
  const int t = threadIdx.x;
  const int d0 = b << 8;
  const int nd = min(256, n - d0);
  const int base = b * CAP;
  const int rcnt = bincur[b];
  if (t < 256) cnt[t] = 0;
  __syncthreads();
  for (int j = t; j < rcnt; j += 1024) {
    unsigned int r = staging[(size_t)base + j];
    atomicAdd(&cnt[r >> 17], 1);
  }
  __syncthreads();
  int v = 0;
  if (t < 256) { v = cnt[t]; cur[t] = v; }
  __syncthreads();
  for (int off = 1; off < 256; off <<= 1) {
    int add = (t < 256 && t >= off) ? cur[t - off] : 0;
    __syncthreads();
    if (t < 256) cur[t] += add;
    __syncthreads();
  }
  if (t < 256) {
    int start = base + cur[t] - v;  // exclusive prefix within bin
    if (t < nd) { rowbeg[d0 + t] = start; rowend[d0 + t] = start + v; }
    cur[t] = start;
  }
  __syncthreads();
  for (int j = t; j < rcnt; j += 1024) {
    unsigned int r = staging[(size_t)base + j];
    int pos = atomicAdd(&cur[r >> 17], 1);
    bucket[pos] = (int)(r & 0x1FFFFu);
  }
}

// ---------------- g1: wave per dst, 8 edges/iter; writes x2 = relu(agg+b1) bf16 ----------------
__global__ __launch_bounds__(256) void g1_kernel(const int* __restrict__ rowbeg,
                                                 const int* __restrict__ rowend,
                                                 const int* __restrict__ bucket,
                                                 const float* __restrict__ asrc,
                                                 const float* __restrict__ adst,
                                                 const unsigned int* __restrict__ h,  // bf16x2, row stride 64
                                                 const float* __restrict__ b1,
                                                 unsigned short* __restrict__ x2,     // bf16 out
                                                 int n) {
  const int lane = threadIdx.x & 63;
  const int g = lane >> 3;
  const int l8 = lane & 7;
  const int head = l8 >> 1;
  const int d = blockIdx.x * 4 + (threadIdx.x >> 6);
  if (d >= n) return;
  const float ad = adst[(size_t)d * 4 + head];
  const int beg = rowbeg[d], end = rowend[d];
  float num[16];
#pragma unroll
  for (int j = 0; j < 16; j++) num[j] = 0.f;
  float den = 0.f;

  int i = beg + g;
  if (i < end) {
    int s = bucket[i];
    for (;;) {
      float a = asrc[(size_t)s * 4 + head];
      const uint4* hp = (const uint4*)(h + (size_t)s * 64 + l8 * 8);
      uint4 h0 = hp[0];
      uint4 h1v = hp[1];
      int i2 = i + 8;
      int s2 = (i2 < end) ? bucket[i2] : 0;
      float w = __expf(leaky(a + ad));
      den += w;
      num[0]  += w * bf2f(h0.x & 0xffffu);  num[1]  += w * bf2f(h0.x >> 16);
      num[2]  += w * bf2f(h0.y & 0xffffu);  num[3]  += w * bf2f(h0.y >> 16);
      num[4]  += w * bf2f(h0.z & 0xffffu);  num[5]  += w * bf2f(h0.z >> 16);
      num[6]  += w * bf2f(h0.w & 0xffffu);  num[7]  += w * bf2f(h0.w >> 16);
      num[8]  += w * bf2f(h1v.x & 0xffffu); num[9]  += w * bf2f(h1v.x >> 16);
      num[10] += w * bf2f(h1v.y & 0xffffu); num[11] += w * bf2f(h1v.y >> 16);
      num[12] += w * bf2f(h1v.z & 0xffffu); num[13] += w * bf2f(h1v.z >> 16);
      num[14] += w * bf2f(h1v.w & 0xffffu); num[15] += w * bf2f(h1v.w >> 16);
      if (i2 >= end) break;
      i = i2; s = s2;
    }
  }
#pragma unroll
  for (int j = 0; j < 16; j++) {
    num[j] += __shfl_xor(num[j], 8, 64);
    num[j] += __shfl_xor(num[j], 16, 64);
    num[j] += __shfl_xor(num[j], 32, 64);
  }
  den += __shfl_xor(den, 8, 64);
  den += __shfl_xor(den, 16, 64);
  den += __shfl_xor(den, 32, 64);
  if (g == 0) {
    float inv = 1.f / (den + 1e-16f);
    const float4* b14 = (const float4*)b1;
    float4 bb[4] = {b14[l8 * 4], b14[l8 * 4 + 1], b14[l8 * 4 + 2], b14[l8 * 4 + 3]};
    const float* bbf = (const float*)bb;
    unsigned short* p = x2 + (size_t)d * 128 + l8 * 16;
    uint4 o0, o1;
    o0.x = pack2(fmaxf(num[0] * inv + bbf[0], 0.f),  fmaxf(num[1] * inv + bbf[1], 0.f));
    o0.y = pack2(fmaxf(num[2] * inv + bbf[2], 0.f),  fmaxf(num[3] * inv + bbf[3], 0.f));
    o0.z = pack2(fmaxf(num[4] * inv + bbf[4], 0.f),  fmaxf(num[5] * inv + bbf[5], 0.f));
    o0.w = pack2(fmaxf(num[6] * inv + bbf[6], 0.f),  fmaxf(num[7] * inv + bbf[7], 0.f));
    o1.x = pack2(fmaxf(num[8] * inv + bbf[8], 0.f),  fmaxf(num[9] * inv + bbf[9], 0.f));
    o1.y = pack2(fmaxf(num[10] * inv + bbf[10], 0.f), fmaxf(num[11] * inv + bbf[11], 0.f));
    o1.z = pack2(fmaxf(num[12] * inv + bbf[12], 0.f), fmaxf(num[13] * inv + bbf[13], 0.f));
    o1.w = pack2(fmaxf(num[14] * inv + bbf[14], 0.f), fmaxf(num[15] * inv + bbf[15], 0.f));
    *(uint4*)p = o0;
    *(uint4*)(p + 8) = o1;
  }
}

// ---------------- GEMM2 (bf16 MFMA): h2 = x2 @ W2 ; a2 dots (x2 pre-activated) ----------------
__global__ __launch_bounds__(256, 2) void gemm2_kernel(const unsigned short* __restrict__ x2,  // bf16
                                                       const float* __restrict__ W,
                                                       const float* __restrict__ atts,
                                                       const float* __restrict__ attd,
                                                       unsigned short* __restrict__ h2,
                                                       float* __restrict__ asrc,
                                                       float* __restrict__ adst, int n) {
  __shared__ __align__(16) unsigned short xs[128 * GSTRIDE];  // x2 tile bf16
  __shared__ __align__(16) unsigned short wt[32 * GSTRIDE];   // W2^T bf16: wt[n][k]
  __shared__ __align__(16) unsigned short hs[128 * 36];       // h2 tile bf16
  __shared__ float att_s[32], att_d[32];
  const int tid = threadIdx.x;
  const int row0 = blockIdx.x * 128;

  if (tid < 32) { att_s[tid] = atts[tid]; att_d[tid] = attd[tid]; }

  const float4* w4 = (const float4*)W;
#pragma unroll
  for (int i = 0; i < 4; i++) {
    int idx = tid + i * 256;
    int k = idx >> 3, n0 = (idx & 7) * 4;
    float4 v = w4[idx];
    float vv[4] = {v.x, v.y, v.z, v.w};
#pragma unroll
    for (int jj = 0; jj < 4; jj++) {
      int j = (jj + tid) & 3;
      wt[(n0 + j) * GSTRIDE + k] = f2bf(vv[j]);
    }
  }

  // stage x2 (already relu'd + biased, bf16): pure copy, 2048 uint4
  const uint4* a4 = (const uint4*)x2;
#pragma unroll
  for (int i = 0; i < 8; i++) {
    int idx = tid + i * 256;        // 2048
    int r = idx >> 4, c8 = (idx & 15) * 8;
    uint4 v = make_uint4(0, 0, 0, 0);
    if (row0 + r < n) v = a4[(size_t)(row0 + r) * 16 + (idx & 15)];
    unsigned int* p = (unsigned int*)&xs[r * GSTRIDE + c8];
    p[0] = v.x; p[1] = v.y; p[2] = v.z; p[3] = v.w;
  }
  __syncthreads();

  const int l = tid & 63;
  const int w = tid >> 6;
  const int mrow = l & 15;
  const int q = l >> 4;
  floatx4 acc[2][2];
#pragma unroll
  for (int mt = 0; mt < 2; mt++)
#pragma unroll
    for (int nt = 0; nt < 2; nt++) acc[mt][nt] = (floatx4){0.f, 0.f, 0.f, 0.f};

#pragma unroll
  for (int ks = 0; ks < 4; ks++) {
    const int k0 = ks * 32 + q * 8;
    short8 a0 = *(const short8*)&xs[(w * 32 + mrow) * GSTRIDE + k0];
    short8 a1 = *(const short8*)&xs[(w * 32 + 16 + mrow) * GSTRIDE + k0];
#pragma unroll
    for (int nt = 0; nt < 2; nt++) {
      short8 b = *(const short8*)&wt[(nt * 16 + mrow) * GSTRIDE + k0];
      acc[0][nt] = __builtin_amdgcn_mfma_f32_16x16x32_bf16(a0, b, acc[0][nt], 0, 0, 0);
      acc[1][nt] = __builtin_amdgcn_mfma_f32_16x16x32_bf16(a1, b, acc[1][nt], 0, 0, 0);
    }
  }

#pragma unroll
  for (int mt = 0; mt < 2; mt++)
#pragma unroll
    for (int nt = 0; nt < 2; nt++)
#pragma unroll
      for (int i = 0; i < 4; i++) {
        int r = w * 32 + mt * 16 + q * 4 + i;
        hs[r * 36 + nt * 16 + mrow] = f2bf(acc[mt][nt][i]);
      }
  __syncthreads();

#pragma unroll
  for (int i = 0; i < 4; i++) {
    int idx = tid + i * 256;        // 1024
    int r = idx >> 3, c4 = (idx & 7) * 4;
    if (row0 + r < n) {
      unsigned int* p = (unsigned int*)&hs[r * 36 + c4];
      *(uint2*)(h2 + (size_t)(row0 + r) * 32 + c4) = make_uint2(p[0], p[1]);
    }
  }

  if (tid < 128) {
    int row = tid;
    float ss = 0.f, sd = 0.f;
#pragma unroll
    for (int c = 0; c < 32; c++) {
      int cr = (c + tid) & 31;
      float hv = bf2f(hs[row * 36 + cr]);
      ss += hv * att_s[cr];
      sd += hv * att_d[cr];
    }
    if (row0 + row < n) { asrc[row0 + row] = ss; adst[row0 + row] = sd; }
  }
}

// ---------------- g2: wave per dst, 8 edges/iter (8-lane groups) ----------------
__global__ __launch_bounds__(256) void g2_kernel(const int* __restrict__ rowbeg,
                                                 const int* __restrict__ rowend,
                                                 const int* __restrict__ bucket,
                                                 const float* __restrict__ asrc,
                                                 const float* __restrict__ adst,
                                                 const unsigned int* __restrict__ h2,  // bf16x2, row stride 16
                                                 const float* __restrict__ b2,
                                                 float* __restrict__ out, int n) {
  const int lane = threadIdx.x & 63;
  const int g = lane >> 3;
  const int l8 = lane & 7;
  const int d = blockIdx.x * 4 + (threadIdx.x >> 6);
  if (d >= n) return;
  const float ad = adst[d];
  const int beg = rowbeg[d], end = rowend[d];
  float num[4];
#pragma unroll
  for (int j = 0; j < 4; j++) num[j] = 0.f;
  float den = 0.f;

  int i = beg + g;
  if (i < end) {
    int s = bucket[i];
    for (;;) {
      float a = asrc[s];
      uint2 hv = *(const uint2*)(h2 + (size_t)s * 16 + l8 * 2);
      int i2 = i + 8;
      int s2 = (i2 < end) ? bucket[i2] : 0;
      float w = __expf(leaky(a + ad));
      den += w;
      num[0] += w * bf2f(hv.x & 0xffffu); num[1] += w * bf2f(hv.x >> 16);
      num[2] += w * bf2f(hv.y & 0xffffu); num[3] += w * bf2f(hv.y >> 16);
      if (i2 >= end) break;
      i = i2; s = s2;
    }
  }
#pragma unroll
  for (int j = 0; j < 4; j++) {
    num[j] += __shfl_xor(num[j], 8, 64);
    num[j] += __shfl_xor(num[j], 16, 64);
    num[j] += __shfl_xor(num[j], 32, 64);
  }
  den += __shfl_xor(den, 8, 64);
  den += __shfl_xor(den, 16, 64);
  den += __shfl_xor(den, 32, 64);
  if (g == 0) {
    float inv = 1.f / (den + 1e-16f);
    float4 bb = ((const float4*)b2)[l8];  // b2: 32 floats = 8 float4; l8 in [0,8)
    *(float4*)(out + (size_t)d * 32 + l8 * 4) =
        make_float4(num[0] * inv + bb.x, num[1] * inv + bb.y,
                    num[2] * inv + bb.z, num[3] * inv + bb.w);
  }
}

extern "C" void kernel_launch(void* const* d_in, const int* in_sizes, int n_in,
                              void* d_out, int out_size, void* d_ws, size_t ws_size,
                              hipStream_t stream) {
  const float* x = (const float*)d_in[0];
  const int* ei = (const int*)d_in[1];
  const float* W1 = (const float*)d_in[2];
  const float* atts1 = (const float*)d_in[3];
  const float* attd1 = (const float*)d_in[4];
  const float* b1 = (const float*)d_in[5];
  const float* W2 = (const float*)d_in[6];
  const float* atts2 = (const float*)d_in[7];
  const float* attd2 = (const float*)d_in[8];
  const float* b2 = (const float*)d_in[9];
  float* out = (float*)d_out;

  const int N = in_sizes[0] / 128;
  const int E = in_sizes[1] / 2;
  const int ET = E + N;
  const int NB = (N + 255) >> 8;            // 391 bins (256 dsts each)
  const int NCH = (ET + CHUNK - 1) / CHUNK; // 416 binA-role blocks
  const int G1B = (N + 127) / 128;          // 782 gemm1-role blocks

  // workspace (~74 MB):
  float* wsf = (float*)d_ws;
  float* asrc1 = wsf;                                   // 4N f
  float* adst1 = asrc1 + (size_t)N * 4;                 // 4N f
  float* asrc2 = adst1 + (size_t)N * 4;                 // N f
  float* adst2 = asrc2 + (size_t)N;                     // N f
  unsigned short* x2 = (unsigned short*)(adst2 + (size_t)N);  // 128N bf16
  unsigned short* h1 = x2 + (size_t)N * 128;            // 128N bf16
  unsigned short* h2 = h1;                              // alias: h1 dead after g1 (h2 = 32N)
  int* rowbeg = (int*)(h1 + (size_t)N * 128);           // N
  int* rowend = rowbeg + N;                             // N
  int* bucket = rowend + N;                             // NB*CAP (fixed-stride space)
  unsigned int* staging = (unsigned int*)(bucket + (size_t)NB * CAP);  // NB*CAP
  int* bincur = (int*)(staging + (size_t)NB * CAP);     // NB

  hipMemsetAsync(bincur, 0, NB * sizeof(int), stream);
  fused1_kernel<<<G1B + NCH, 256, 0, stream>>>(x, W1, atts1, attd1, h1, asrc1, adst1,
                                               N, G1B, ei, bincur, staging, E, ET, NB);
  binB_kernel<<<NB, 1024, 0, stream>>>(staging, bincur, rowbeg, rowend, bucket, N);
  g1_kernel<<<(N + 3) / 4, 256, 0, stream>>>(rowbeg, rowend, bucket, asrc1, adst1,
                                             (const unsigned int*)h1, b1, x2, N);
  gemm2_kernel<<<(N + 127) / 128, 256, 0, stream>>>(x2, W2, atts2, attd2,
                                                    h2, asrc2, adst2, N);
  g2_kernel<<<(N + 3) / 4, 256, 0, stream>>>(rowbeg, rowend, bucket, asrc2, adst2,
                                             (const unsigned int*)h2, b2, out, N);
}